// Round 1
// 279.322 us; speedup vs baseline: 1.2654x; 1.2654x over previous
//
#include <hip/hip_runtime.h>

#define N_PTS 20000
#define DIMS  128
#define A_CNT 1024
#define KNEG  10
#define NTILES 157              // ceil(20000/128)
#define NCHUNK (NTILES * 16)    // 2512 chunk-of-8 slots per (side, anchor)
#define NCHUNK_REAL 2500        // 20000/8 — chunks >=2500 are pure padding
#define BIGV  1e18f
#define BIGI  0x7F000000
#define CAND_CAP 768
#define PT_CAP   768

// v_sad_u8: d = c + sum_{i=0..3} |a.byte[i] - b.byte[i]|  (4 dims per VALU op)
__device__ __forceinline__ unsigned int sad_u8(unsigned int a, unsigned int b, unsigned int c) {
#if __has_builtin(__builtin_amdgcn_sad_u8)
    return __builtin_amdgcn_sad_u8(a, b, c);
#else
    unsigned int d;
    asm("v_sad_u8 %0, %1, %2, %3" : "=v"(d) : "v"(a), "v"(b), "v"(c));
    return d;
#endif
}

// ---------------------------------------------------------------------------
// absmax over both fp32 arrays (bit-pattern atomicMax valid for non-neg fp32)
// ---------------------------------------------------------------------------
__global__ void absmax_kernel(const float* __restrict__ a, const float* __restrict__ b,
                              unsigned int* __restrict__ amax) {
    const int n4 = N_PTS * DIMS / 4;
    const int stride = gridDim.x * blockDim.x;
    float m = 0.f;
    for (int i = blockIdx.x * blockDim.x + threadIdx.x; i < 2 * n4; i += stride) {
        const float4 v = (i < n4) ? ((const float4*)a)[i] : ((const float4*)b)[i - n4];
        m = fmaxf(m, fmaxf(fmaxf(fabsf(v.x), fabsf(v.y)), fmaxf(fabsf(v.z), fabsf(v.w))));
    }
#pragma unroll
    for (int s = 1; s < 64; s <<= 1) m = fmaxf(m, __shfl_xor(m, s, 64));
    if ((threadIdx.x & 63) == 0) atomicMax(amax, __float_as_uint(m));
}

// ---------------------------------------------------------------------------
// quantize q = rint(127*v/M + 127) in [0,254]; also emit per-row residual sum
// R = sum_d |q_d - (s*v_d+127)| + 1.0 margin, and global Rmax.
// 8 threads per row, 16 dims each.
// ---------------------------------------------------------------------------
__global__ void quantR_kernel(const float* __restrict__ src, unsigned int* __restrict__ dst,
                              float* __restrict__ Rrow, const unsigned int* __restrict__ amaxBits,
                              unsigned int* __restrict__ rmaxBits) {
    const int g = blockIdx.x * 256 + threadIdx.x;
    const int row = g >> 3;
    const int sub = g & 7;
    if (row >= N_PTS) return;
    const float M = __uint_as_float(*amaxBits);
    const float s = 127.0f / M;
    const float4* s4 = (const float4*)(src + (size_t)row * DIMS + sub * 16);
    unsigned int* d = dst + (size_t)row * 32 + sub * 4;
    float rs = 0.f;
#pragma unroll
    for (int m = 0; m < 4; ++m) {
        const float4 v = s4[m];
        const float f0 = v.x * s + 127.0f, f1 = v.y * s + 127.0f;
        const float f2 = v.z * s + 127.0f, f3 = v.w * s + 127.0f;
        const float q0 = rintf(f0), q1 = rintf(f1), q2 = rintf(f2), q3 = rintf(f3);
        rs += fabsf(q0 - f0) + fabsf(q1 - f1) + fabsf(q2 - f2) + fabsf(q3 - f3);
        d[m] = (unsigned int)q0 | ((unsigned int)q1 << 8) |
               ((unsigned int)q2 << 16) | ((unsigned int)q3 << 24);
    }
    rs += __shfl_xor(rs, 1, 64);
    rs += __shfl_xor(rs, 2, 64);
    rs += __shfl_xor(rs, 4, 64);
    if (sub == 0) {
        const float R = rs + 1.0f;   // margin for fp rounding in s*v
        Rrow[row] = R;
        atomicMax(rmaxBits, __float_as_uint(R));
    }
}

// ---------------------------------------------------------------------------
// SAD distance kernel: 64 anchors x 128 points per block, 4x8 per thread.
// (unchanged this round — next round's top-5 counters will expose it)
// ---------------------------------------------------------------------------
__global__ __launch_bounds__(256, 4)
void dist_sad_kernel(const unsigned int* __restrict__ q1, const unsigned int* __restrict__ q2,
                     const int* __restrict__ anchor1, const int* __restrict__ anchor2,
                     unsigned short* __restrict__ minOut) {
    __shared__ unsigned int sA[64 * 32];
    __shared__ unsigned int sP[128 * 32];

    const int tile = blockIdx.x;    // 0..156
    const int ag   = blockIdx.y;    // 0..15 (groups of 64 anchors)
    const int side = blockIdx.z;    // 0..1

    const unsigned int* aData = side ? q2 : q1;
    const unsigned int* pData = side ? q1 : q2;
    const int*          aIdx  = side ? anchor2 : anchor1;

    const int tid = threadIdx.x;
    const int tx = tid & 15;        // point chunk (8 pts)
    const int ty = tid >> 4;        // anchor chunk (4 anchors)

    // staging A: 64 rows, 4 threads/row, 2 uint4 each (blocks qa, qa+4)
    {
        const int ra = tid >> 2;
        const int qa = tid & 3;
        const unsigned int* aRow = aData + (size_t)aIdx[ag * 64 + ra] * 32;
        const uint4 v0 = *(const uint4*)(aRow + qa * 4);
        const uint4 v1 = *(const uint4*)(aRow + (qa + 4) * 4);
        const int rot = ra >> 3;
        *(uint4*)&sA[ra * 32 + (((qa + rot) & 7) << 2)]     = v0;
        *(uint4*)&sA[ra * 32 + (((qa + 4 + rot) & 7) << 2)] = v1;
    }
    // staging P: 128 rows, 2 threads/row, 4 uint4 each
    {
        const int rp = tid >> 1;
        const int h  = tid & 1;
        const int prow = tile * 128 + rp;
        const bool pvalid = prow < N_PTS;
        const uint4* pRow4 = (const uint4*)(pData + (size_t)prow * 32 + h * 16);
        const int rot = rp >> 3;
#pragma unroll
        for (int j = 0; j < 4; ++j) {
            const uint4 v = pvalid ? pRow4[j]
                                   : make_uint4(0xFFFFFFFFu, 0xFFFFFFFFu, 0xFFFFFFFFu, 0xFFFFFFFFu);
            const int blk = h * 4 + j;
            *(uint4*)&sP[rp * 32 + (((blk + rot) & 7) << 2)] = v;
        }
    }
    __syncthreads();

    unsigned int acc[4][8];
#pragma unroll
    for (int i = 0; i < 4; ++i)
#pragma unroll
        for (int j = 0; j < 8; ++j) acc[i][j] = 0u;

    const int ty4 = ty * 4;
    const int tx8 = tx * 8;

#pragma unroll 2
    for (int bk = 0; bk < 8; ++bk) {
        uint4 A[4], P[8];
        const int aslot = ((bk + (ty >> 1)) & 7) << 2;   // rot(ty*4+i) = ty>>1
        const int pslot = ((bk + tx) & 7) << 2;          // rot(tx*8+j) = tx
#pragma unroll
        for (int i = 0; i < 4; ++i) A[i] = *(const uint4*)&sA[(ty4 + i) * 32 + aslot];
#pragma unroll
        for (int j = 0; j < 8; ++j) P[j] = *(const uint4*)&sP[(tx8 + j) * 32 + pslot];
#pragma unroll
        for (int i = 0; i < 4; ++i)
#pragma unroll
            for (int j = 0; j < 8; ++j) {
                unsigned int s = sad_u8(A[i].x, P[j].x, acc[i][j]);
                s = sad_u8(A[i].y, P[j].y, s);
                s = sad_u8(A[i].z, P[j].z, s);
                acc[i][j] = sad_u8(A[i].w, P[j].w, s);
            }
    }

    const size_t outBase = (size_t)side * A_CNT * NCHUNK;
#pragma unroll
    for (int i = 0; i < 4; ++i) {
        unsigned int m = min(min(min(acc[i][0], acc[i][1]), min(acc[i][2], acc[i][3])),
                             min(min(acc[i][4], acc[i][5]), min(acc[i][6], acc[i][7])));
        minOut[outBase + (size_t)(ag * 64 + ty4 + i) * NCHUNK + tile * 16 + tx] =
            (unsigned short)m;
    }
}

// ---------------------------------------------------------------------------
// branchless sorted insert into ascending top-10 (int) — used only for the
// chunk-min m10 bound (Phase A). The float merge machinery is gone: Phase D
// now rank-counts against an LDS distance list instead.
// ---------------------------------------------------------------------------
__device__ __forceinline__ void insert10i(int (&t)[10], int v) {
    if (v < t[9]) {
#pragma unroll
        for (int i = 9; i >= 1; --i) t[i] = min(t[i], max(t[i - 1], v));
        t[0] = min(t[0], v);
    }
}
__device__ __forceinline__ void mergeTop10i(int (&t)[10]) {
    for (int s = 1; s < 64; s <<= 1) {
        int o[10];
#pragma unroll
        for (int k = 0; k < 10; ++k) o[k] = __shfl_xor(t[k], s, 64);
#pragma unroll
        for (int k = 0; k < 10; ++k) insert10i(t, o[k]);
    }
}

// ---------------------------------------------------------------------------
// select: one 256-thread block (4 waves) per (side, anchor).
//  A: m10 = 10th smallest chunk-min (block-wide merge)
//  thr = m10 + 2*R_a + 2*Rmax + 4   [proof: |d_int - s*d| <= R_a+R_p <= R_a+Rmax;
//   >=10 pts have d_int <= m10 -> s*D10 <= m10+R_a+Rmax; top-10 p:
//   d_int(p) <= s*D10+R_a+Rmax <= m10+2R_a+2Rmax]
//  B: candidate chunks; C: per-point u8 SAD filter, 4 chunks in flight per
//  wave iteration (4x MLP on the L3-latency-bound gather);
//  D: exact fp32 recompute (4 threads/point) -> distances to LDS ->
//  rank-count top-10 -> loss. Exact result.
// ---------------------------------------------------------------------------
__global__ __launch_bounds__(256, 4)
void select_kernel(const float* __restrict__ out1, const float* __restrict__ out2,
                   const unsigned int* __restrict__ q1, const unsigned int* __restrict__ q2,
                   const int* __restrict__ anchor1, const int* __restrict__ anchor2,
                   const unsigned short* __restrict__ minIn,
                   const float* __restrict__ R1, const float* __restrict__ R2,
                   const unsigned int* __restrict__ rmaxBits, float* __restrict__ out) {
    const int bid = blockIdx.x;          // 0..2047
    const int side = bid >> 10;
    const int ai = bid & 1023;
    const int tid = threadIdx.x;
    const int lane = tid & 63;
    const int wv = tid >> 6;

    const float* aDataF = side ? out2 : out1;
    const float* pDataF = side ? out1 : out2;
    const unsigned int* aDataQ = side ? q2 : q1;
    const unsigned int* pDataQ = side ? q1 : q2;
    const float* Ranc = side ? R2 : R1;
    const int* aIdx = side ? anchor2 : anchor1;

    __shared__ float aRowF[DIMS];
    __shared__ int candCount, pointCount;
    __shared__ int candList[CAND_CAP];
    __shared__ int ptList[PT_CAP];
    __shared__ float sDist[PT_CAP];
    __shared__ int wtI[4][10];
    __shared__ float wSum[4];
    __shared__ float sThr, sDm;

    const int arow = aIdx[ai];
    if (tid < DIMS) aRowF[tid] = aDataF[(size_t)arow * DIMS + tid];
    const uint4 qa4 = ((const uint4*)(aDataQ + (size_t)arow * 32))[lane & 7];
    if (tid == 0) { candCount = 0; pointCount = 0; }

    // Dm (wave 0 only)
    if (wv == 0) {
        const int r1 = anchor1[ai], r2 = anchor2[ai];
        const float2 x1 = ((const float2*)(out1 + (size_t)r1 * DIMS))[lane];
        const float2 x2 = ((const float2*)(out2 + (size_t)r2 * DIMS))[lane];
        float dm = fabsf(x1.x - x2.x) + fabsf(x1.y - x2.y);
#pragma unroll
        for (int s = 1; s < 64; s <<= 1) dm += __shfl_xor(dm, s, 64);
        if (lane == 0) sDm = dm + 1.0f;   // GAMMA
    }

    // Phase A: chunk minima -> block-wide m10
    const unsigned short* mbase = minIn + ((size_t)side * A_CNT + ai) * NCHUNK;
    int mv[10];
#pragma unroll
    for (int j = 0; j < 10; ++j) {
        const int c = tid + 256 * j;
        mv[j] = (c < NCHUNK_REAL) ? (int)mbase[c] : BIGI;
    }
    int t[10];
#pragma unroll
    for (int k = 0; k < 10; ++k) t[k] = BIGI;
#pragma unroll
    for (int j = 0; j < 10; ++j) insert10i(t, mv[j]);
    mergeTop10i(t);
    if (lane == 0)
#pragma unroll
        for (int k = 0; k < 10; ++k) wtI[wv][k] = t[k];
    __syncthreads();
    if (wv == 0) {
        int t3[10];
#pragma unroll
        for (int k = 0; k < 10; ++k) t3[k] = BIGI;
        t3[0] = (lane < 40) ? wtI[lane / 10][lane % 10] : BIGI;
        mergeTop10i(t3);
        if (lane == 0) {
            const float Ra = Ranc[arow];
            const float Rmax = __uint_as_float(*rmaxBits);
            sThr = (float)t3[9] + 2.0f * Ra + 2.0f * Rmax + 4.0f;
        }
    }
    __syncthreads();
    const float thr = sThr;

    // Phase B: candidate chunks
#pragma unroll
    for (int j = 0; j < 10; ++j) {
        const int c = tid + 256 * j;
        if (c < NCHUNK_REAL && (float)mv[j] <= thr) {
            const int pos = atomicAdd(&candCount, 1);
            if (pos < CAND_CAP) candList[pos] = c;
        }
    }
    __syncthreads();
    const int cc = min(candCount, CAND_CAP);

    // Phase C: per-point u8 SAD filter, 4 chunks in flight per wave iteration.
    // Wave wv owns cand slots [wv*4+16k, wv*4+16k+3] — 4 independent 16B
    // gathers issued before any reduce (MLP x4 on the ~L3-latency load).
    const int psub = lane >> 3;
    const int seg  = lane & 7;
    for (int s0 = wv * 4; s0 < cc; s0 += 16) {
        uint4 qp[4];
        int ptv[4];
#pragma unroll
        for (int u = 0; u < 4; ++u) {
            const int s = s0 + u;
            const int c = candList[(s < cc) ? s : s0];   // dup-load for tail, output guarded
            ptv[u] = c * 8 + psub;                       // c < 2500 -> pt < 20000 always
            qp[u] = ((const uint4*)(pDataQ + (size_t)ptv[u] * 32))[seg];
        }
#pragma unroll
        for (int u = 0; u < 4; ++u) {
            unsigned int d = sad_u8(qa4.x, qp[u].x, 0u);
            d = sad_u8(qa4.y, qp[u].y, d);
            d = sad_u8(qa4.z, qp[u].z, d);
            d = sad_u8(qa4.w, qp[u].w, d);
            int di = (int)d;
            di += __shfl_xor(di, 1, 64);
            di += __shfl_xor(di, 2, 64);
            di += __shfl_xor(di, 4, 64);
            if ((s0 + u) < cc && seg == 0 && (float)di <= thr) {
                const int pos = atomicAdd(&pointCount, 1);
                if (pos < PT_CAP) ptList[pos] = ptv[u];
            }
        }
    }
    __syncthreads();
    const int pc = min(pointCount, PT_CAP);

    // Phase D: exact fp32 distances, 4 threads per point (8 float4 loads each,
    // 4x the active lanes vs 1-thread-per-point), result -> sDist[idx].
    const int pt4 = tid >> 2;
    const int qq  = tid & 3;
    for (int base = 0; base < pc; base += 64) {
        const int idx = base + pt4;
        float s01 = 0.f, s23 = 0.f;
        if (idx < pc) {
            const int pt = ptList[idx];
            const float4* p4 = (const float4*)(pDataF + (size_t)pt * DIMS) + qq * 8;
            const float4* a4 = ((const float4*)aRowF) + qq * 8;
#pragma unroll
            for (int q = 0; q < 8; ++q) {
                const float4 pv = p4[q];
                const float4 av = a4[q];
                s01 += fabsf(av.x - pv.x) + fabsf(av.y - pv.y);
                s23 += fabsf(av.z - pv.z) + fabsf(av.w - pv.w);
            }
        }
        float s = s01 + s23;
        s += __shfl_xor(s, 1, 64);
        s += __shfl_xor(s, 2, 64);
        if (qq == 0 && idx < pc) sDist[idx] = s;
    }
    __syncthreads();

    // Rank-count top-10: each thread owns <=3 survivors (static slots, rule #20),
    // streams the broadcast LDS list once; lexicographic (value,index) order
    // makes ranks unique, so exactly KNEG slots have rank < KNEG (pc >= 10 is
    // guaranteed: every true top-10 point passes the filters).
    const float dm = sDm;
    const int i0 = tid, i1 = tid + 256, i2 = tid + 512;
    float v0 = BIGV, v1 = BIGV, v2 = BIGV;
    if (i0 < pc) v0 = sDist[i0];
    if (i1 < pc) v1 = sDist[i1];
    if (i2 < pc) v2 = sDist[i2];
    int r0 = 0, r1 = 0, r2 = 0;
    for (int j = 0; j < pc; ++j) {
        const float vj = sDist[j];
        r0 += (vj < v0) || (vj == v0 && j < i0);
        r1 += (vj < v1) || (vj == v1 && j < i1);
        r2 += (vj < v2) || (vj == v2 && j < i2);
    }
    float contrib = 0.f;
    if (i0 < pc && r0 < KNEG) contrib += fmaxf(dm - v0, 0.f);
    if (i1 < pc && r1 < KNEG) contrib += fmaxf(dm - v1, 0.f);
    if (i2 < pc && r2 < KNEG) contrib += fmaxf(dm - v2, 0.f);
#pragma unroll
    for (int s = 1; s < 64; s <<= 1) contrib += __shfl_xor(contrib, s, 64);
    if (lane == 0) wSum[wv] = contrib;
    __syncthreads();
    if (tid == 0)
        atomicAdd(out, (wSum[0] + wSum[1] + wSum[2] + wSum[3]) * (1.0f / (A_CNT * KNEG)));
}

extern "C" void kernel_launch(void* const* d_in, const int* in_sizes, int n_in,
                              void* d_out, int out_size, void* d_ws, size_t ws_size,
                              hipStream_t stream) {
    const float* out1    = (const float*)d_in[0];
    const float* out2    = (const float*)d_in[1];
    const int*   anchor1 = (const int*)d_in[2];
    const int*   anchor2 = (const int*)d_in[3];
    float* out = (float*)d_out;

    // ws: q1 | q2 | minbuf u16 | R1 | R2 | amax | rmax  (~15.6 MB)
    unsigned int* q1 = (unsigned int*)d_ws;
    unsigned int* q2 = q1 + (size_t)N_PTS * DIMS / 4;
    unsigned short* minbuf = (unsigned short*)(q2 + (size_t)N_PTS * DIMS / 4);
    float* R1 = (float*)(minbuf + (size_t)2 * A_CNT * NCHUNK);
    float* R2 = R1 + N_PTS;
    unsigned int* amax = (unsigned int*)(R2 + N_PTS);
    unsigned int* rmax = amax + 1;

    hipMemsetAsync(out, 0, sizeof(float), stream);
    hipMemsetAsync(amax, 0, 2 * sizeof(unsigned int), stream);

    hipLaunchKernelGGL(absmax_kernel, dim3(256), dim3(256), 0, stream, out1, out2, amax);
    const int qblocks = (N_PTS * 8 + 255) / 256;   // 8 threads per row
    hipLaunchKernelGGL(quantR_kernel, dim3(qblocks), dim3(256), 0, stream, out1, q1, R1, amax, rmax);
    hipLaunchKernelGGL(quantR_kernel, dim3(qblocks), dim3(256), 0, stream, out2, q2, R2, amax, rmax);

    dim3 gridA(NTILES, 16, 2);
    hipLaunchKernelGGL(dist_sad_kernel, gridA, dim3(256), 0, stream,
                       q1, q2, anchor1, anchor2, minbuf);
    hipLaunchKernelGGL(select_kernel, dim3(2048), dim3(256), 0, stream,
                       out1, out2, q1, q2, anchor1, anchor2, minbuf, R1, R2, rmax, out);
}